// Round 8
// baseline (4245.533 us; speedup 1.0000x reference)
//
#include <hip/hip_runtime.h>
#include <cstdint>

#define NBATCH 16
#define NPOINT 1024
#define NPTS   100000
#define GPB    16            // blocks per batch
#define TPB    256           // threads per block (4 waves)
#define WPB    4
#define NSLOT  (GPB * WPB)   // 64 wave-level slots per batch
#define NSUB   16            // sub-blocks per batch in precompute kernels
#define STRIDE (GPB * TPB)   // 4096 threads per batch
#define KPT    25            // points per thread
#define NPAIR  13            // KPT as float pairs (last half-padded)

typedef unsigned long long u64;

// d_ws layout (no host memset needed):
//   @0    : float psum[16][16][4]  (4 KB)  — per-(batch,sub) partial coord sums (plain stores)
//   @4096 : uint  pmax[16][16]     (1 KB)  — per-(batch,sub) partial max sq-radius (plain stores)
//   @8192 : u64   slots[2][16][64] (16 KB) — per-(parity,batch,wave) argmax msg;
//                                            zeroed by max_kernel block 0 (poisoned seq would
//                                            false-accept, so this clear is mandatory)

// ---------------- precompute 1: per-(batch,sub) coordinate sums ----------------
__global__ __launch_bounds__(256) void sum_kernel(const float* __restrict__ xyz,
                                                  float* __restrict__ psum) {
    const int b   = blockIdx.x & 15;
    const int sub = blockIdx.x >> 4;          // 0..15
    const float* P = xyz + (size_t)b * NPTS * 3;
    float sx = 0.f, sy = 0.f, sz = 0.f;
    for (int i = sub * TPB + threadIdx.x; i < NPTS; i += NSUB * TPB) {
        sx += P[i * 3 + 0];
        sy += P[i * 3 + 1];
        sz += P[i * 3 + 2];
    }
    #pragma unroll
    for (int off = 32; off; off >>= 1) {
        sx += __shfl_xor(sx, off);
        sy += __shfl_xor(sy, off);
        sz += __shfl_xor(sz, off);
    }
    __shared__ float r[3][4];
    const int wave = threadIdx.x >> 6, lane = threadIdx.x & 63;
    if (lane == 0) { r[0][wave] = sx; r[1][wave] = sy; r[2][wave] = sz; }
    __syncthreads();
    if (threadIdx.x == 0) {
        float* o = psum + (b * NSUB + sub) * 4;
        o[0] = r[0][0] + r[0][1] + r[0][2] + r[0][3];
        o[1] = r[1][0] + r[1][1] + r[1][2] + r[1][3];
        o[2] = r[2][0] + r[2][1] + r[2][2] + r[2][3];
    }
}

// -------- precompute 2: per-(batch,sub) max squared radius + slot clear --------
__global__ __launch_bounds__(256) void max_kernel(const float* __restrict__ xyz,
                                                  const float* __restrict__ psum,
                                                  unsigned* __restrict__ pmax,
                                                  u64* __restrict__ slots) {
    if (blockIdx.x == 0) {                    // clear the 2048 slot words (8 per thread)
        #pragma unroll
        for (int q = 0; q < 8; ++q) slots[threadIdx.x + q * 256] = 0ull;
    }
    const int b   = blockIdx.x & 15;
    const int sub = blockIdx.x >> 4;
    const float* P = xyz + (size_t)b * NPTS * 3;
    float sx = 0.f, sy = 0.f, sz = 0.f;
    #pragma unroll
    for (int s = 0; s < NSUB; ++s) {          // fixed order: deterministic mean for all blocks
        sx += psum[(b * NSUB + s) * 4 + 0];
        sy += psum[(b * NSUB + s) * 4 + 1];
        sz += psum[(b * NSUB + s) * 4 + 2];
    }
    const float mx = sx / (float)NPTS, my = sy / (float)NPTS, mz = sz / (float)NPTS;
    float best = 0.f;
    for (int i = sub * TPB + threadIdx.x; i < NPTS; i += NSUB * TPB) {
        float dx = P[i * 3 + 0] - mx;
        float dy = P[i * 3 + 1] - my;
        float dz = P[i * 3 + 2] - mz;
        best = fmaxf(best, dx * dx + dy * dy + dz * dz);
    }
    #pragma unroll
    for (int off = 32; off; off >>= 1) best = fmaxf(best, __shfl_xor(best, off));
    __shared__ float r[4];
    const int wave = threadIdx.x >> 6, lane = threadIdx.x & 63;
    if (lane == 0) r[wave] = best;
    __syncthreads();
    if (threadIdx.x == 0)
        pmax[b * NSUB + sub] = __float_as_uint(fmaxf(fmaxf(r[0], r[1]), fmaxf(r[2], r[3])));
}

// ---------------- main: FPS, wave-level slots, one barrier per iteration ----------------
// Message word: [63:54] seq (=i+1), [53:22] float bits of max distance (>=0),
//               [21:0]  0x3FFFFF - idx (max-compare => smallest index on ties = np.argmax).
// Parity double-buffer: at iter i the message (seq i+1) goes to parity i&1, so a slot a
// poller of seq i+1 watches can only hold seq i-1 (rejected), i+1, or i+3. Lag<=1 proof
// (one syncB per iter): a seq i+3 store requires its wave to pass syncB(i+1) => its block's
// wave 0 finished poll(i+1) => all waves stored seq i+2 => all waves passed syncB(i) =>
// every block's wave 0 finished poll(i, want=i+1). So the >= gate only ever accepts seq i+1.
__global__ __launch_bounds__(256, 1) void fps_kernel(const float* __restrict__ xyz,
                                                     const float* __restrict__ cmap,
                                                     const int* __restrict__ init_far,
                                                     const unsigned* __restrict__ pmax,
                                                     u64* __restrict__ slots,
                                                     float* __restrict__ out) {
    const int b   = blockIdx.x & 15;   // batch
    const int g   = blockIdx.x >> 4;   // block-in-batch 0..15
    const int tid = threadIdx.x;
    const int wave = tid >> 6, lane = tid & 63;
    const int tl  = g * TPB + tid;     // batch-local lane 0..4095
    const float* P = xyz + (size_t)b * NPTS * 3;

    // s_obj: deterministic reduce over the 16 partial maxes
    float m0 = 0.f;
    #pragma unroll
    for (int s = 0; s < NSUB; ++s) m0 = fmaxf(m0, __uint_as_float(pmax[b * NSUB + s]));
    const float sb = sqrtf(m0);

    // register-resident points (pairs, SLP-vectorizes to v_pk_* fp32) + running distances
    float pxx[NPAIR], pxy[NPAIR], pyx[NPAIR], pyy[NPAIR],
          pzx[NPAIR], pzy[NPAIR], pdx[NPAIR], pdy[NPAIR];
    #pragma unroll
    for (int j = 0; j < NPAIR; ++j) {
        const int p0 = tl + (2 * j) * STRIDE;
        const int p1 = tl + (2 * j + 1) * STRIDE;
        const bool v0 = p0 < NPTS, v1 = p1 < NPTS;
        pxx[j] = v0 ? P[p0 * 3 + 0] : 0.f;  pxy[j] = v1 ? P[p1 * 3 + 0] : 0.f;
        pyx[j] = v0 ? P[p0 * 3 + 1] : 0.f;  pyy[j] = v1 ? P[p1 * 3 + 1] : 0.f;
        pzx[j] = v0 ? P[p0 * 3 + 2] : 0.f;  pzy[j] = v1 ? P[p1 * 3 + 2] : 0.f;
        pdx[j] = v0 ? 1e10f : -1.0f;        pdy[j] = v1 ? 1e10f : -1.0f;
        // every lane owns >=24 valid points -> per-lane best always >= 0
    }

    __shared__ int   lds_win;
    __shared__ float lds_x, lds_y, lds_z;
    __shared__ int   curhist[NPOINT];  // every block records the full selection history

    int cur = init_far[b];
    float cx = P[cur * 3 + 0], cy = P[cur * 3 + 1], cz = P[cur * 3 + 2];

    for (int i = 0; i < NPOINT; ++i) {
        if (tid == 192) curhist[i] = cur;          // wave 3, LDS only — off critical path
        if (i == NPOINT - 1) break;

        // ---- distance update + per-lane argmax (exact fp order match: no fma/contract) ----
        float best = -1.0f;
        int bidx = 0;
        {
            #pragma clang fp contract(off)
            #pragma unroll
            for (int j = 0; j < NPAIR; ++j) {
                float dx0 = pxx[j] - cx, dx1 = pxy[j] - cx;
                float dy0 = pyx[j] - cy, dy1 = pyy[j] - cy;
                float dz0 = pzx[j] - cz, dz1 = pzy[j] - cz;
                float s0 = dx0 * dx0 + dy0 * dy0;  float s1 = dx1 * dx1 + dy1 * dy1;
                s0 = s0 + dz0 * dz0;               s1 = s1 + dz1 * dz1;
                float n0 = fminf(pdx[j], s0);      float n1 = fminf(pdy[j], s1);
                pdx[j] = n0;                       pdy[j] = n1;
                if (n0 > best) { best = n0; bidx = tl + (2 * j) * STRIDE; }      // strict >
                if (n1 > best) { best = n1; bidx = tl + (2 * j + 1) * STRIDE; }  // => first max
            }
        }

        // ---- wave argmax (u64 butterfly; inverted idx -> smallest index on ties) ----
        const u64 want = (u64)(i + 1);
        u64 key = ((u64)__float_as_uint(best) << 22) | (u64)(0x3FFFFFu - (unsigned)bidx);
        #pragma unroll
        for (int off = 32; off; off >>= 1) {
            u64 o2 = __shfl_xor(key, off);
            key = o2 > key ? o2 : key;
        }

        // ---- publish wave-level slot IMMEDIATELY (no barrier, no block reduce) ----
        u64* const bs = slots + ((size_t)(i & 1) * NBATCH + b) * NSLOT;
        if (lane == 0)
            __hip_atomic_store(&bs[g * WPB + wave], key | (want << 54),
                               __ATOMIC_RELAXED, __HIP_MEMORY_SCOPE_AGENT);

        if (wave == 0) {
            // poll all 64 wave-slots: one coalesced 64-lane load + one waitcnt per round
            u64 v;
            {
                u64* sp = &bs[lane];
                int tries = 0;
                for (;;) {
                    v = __hip_atomic_load(sp, __ATOMIC_RELAXED, __HIP_MEMORY_SCOPE_AGENT);
                    if ((v >> 54) >= want) break;
                    if (++tries > 16) __builtin_amdgcn_s_sleep(1);
                }
            }
            // prefetch candidate coords (L2-hot) BEFORE the reduce — hides the gather
            const int ci = (int)(0x3FFFFFu - (unsigned)(v & 0x3FFFFFu));
            const float gx = P[ci * 3 + 0];
            const float gy = P[ci * 3 + 1];
            const float gz = P[ci * 3 + 2];
            // 6-hop argmax over the 64 slot words (all same seq -> u64 max == key max)
            u64 kk = v;
            #pragma unroll
            for (int off = 32; off; off >>= 1) {
                u64 o2 = __shfl_xor(kk, off);
                kk = o2 > kk ? o2 : kk;
            }
            // winner lane self-identifies (idx unique across waves) and writes LDS directly
            if (v == kk) {
                lds_win = ci;
                lds_x = gx; lds_y = gy; lds_z = gz;
            }
        }
        __syncthreads();   // the single barrier per iteration
        cur = lds_win;
        cx = lds_x; cy = lds_y; cz = lds_z;   // coords from the poller's prefetch — no gather
    }

    // ---------------- deferred output pass: 64 rows per block ----------------
    __syncthreads();                   // curhist fully written
    if (tid < 64) {
        const int row = g * 64 + tid;  // 16 blocks x 64 rows = 1024
        const int c   = curhist[row];
        const float cm = cmap[(size_t)b * NPTS + c];
        const float x = P[c * 3 + 0], y = P[c * 3 + 1], z = P[c * 3 + 2];
        float* o = out + ((size_t)b * NPOINT + row) * 4;
        o[0] = cm;
        o[1] = x / sb;
        o[2] = y / sb;
        o[3] = z / sb;
    }
}

extern "C" void kernel_launch(void* const* d_in, const int* in_sizes, int n_in,
                              void* d_out, int out_size, void* d_ws, size_t ws_size,
                              hipStream_t stream) {
    const float* mesh = (const float*)d_in[0];
    const float* cmap = (const float*)d_in[1];
    const int* init   = (const int*)d_in[2];
    float* out = (float*)d_out;

    char* ws      = (char*)d_ws;
    float* psum   = (float*)ws;
    unsigned* pmx = (unsigned*)(ws + 4096);
    u64* slots    = (u64*)(ws + 8192);

    sum_kernel<<<dim3(256), dim3(TPB), 0, stream>>>(mesh, psum);
    max_kernel<<<dim3(256), dim3(TPB), 0, stream>>>(mesh, psum, pmx, slots);
    fps_kernel<<<dim3(256), dim3(TPB), 0, stream>>>(mesh, cmap, init, pmx, slots, out);
}

// Round 9
// 2455.568 us; speedup vs baseline: 1.7289x; 1.7289x over previous
//
#include <hip/hip_runtime.h>
#include <cstdint>

#define NBATCH 16
#define NPOINT 1024
#define NPTS   100000
#define GPB    8             // blocks per batch (8 writers / 8 slots: half a cache line)
#define TPB    512           // threads per block (8 waves)
#define WPB    8
#define SLOTPAD 16           // u64s per (parity,batch) slot group -> one full 128-B line
#define NSUB   16            // sub-blocks per batch in precompute kernels
#define STRIDE (GPB * TPB)   // 4096 threads per batch
#define KPT    25            // points per thread
#define NPAIR  13            // KPT as float pairs (last half-padded)

typedef unsigned long long u64;

// d_ws layout (no host memset needed):
//   @0    : float psum[16][16][4]     (4 KB) — per-(batch,sub) partial coord sums (plain stores)
//   @4096 : uint  pmax[16][16]        (1 KB) — per-(batch,sub) partial max sq-radius (plain stores)
//   @8192 : u64   slots[2][16][16]    (4 KB) — per-(parity,batch) 128-B line; first 8 words used
//                                              (one line per group: batches never share a line);
//                                              zeroed by max_kernel block 0 (poisoned seq would
//                                              false-accept, so this clear is mandatory)

// ---------------- precompute 1: per-(batch,sub) coordinate sums ----------------
__global__ __launch_bounds__(256) void sum_kernel(const float* __restrict__ xyz,
                                                  float* __restrict__ psum) {
    const int b   = blockIdx.x & 15;
    const int sub = blockIdx.x >> 4;          // 0..15
    const float* P = xyz + (size_t)b * NPTS * 3;
    float sx = 0.f, sy = 0.f, sz = 0.f;
    for (int i = sub * 256 + threadIdx.x; i < NPTS; i += NSUB * 256) {
        sx += P[i * 3 + 0];
        sy += P[i * 3 + 1];
        sz += P[i * 3 + 2];
    }
    #pragma unroll
    for (int off = 32; off; off >>= 1) {
        sx += __shfl_xor(sx, off);
        sy += __shfl_xor(sy, off);
        sz += __shfl_xor(sz, off);
    }
    __shared__ float r[3][4];
    const int wave = threadIdx.x >> 6, lane = threadIdx.x & 63;
    if (lane == 0) { r[0][wave] = sx; r[1][wave] = sy; r[2][wave] = sz; }
    __syncthreads();
    if (threadIdx.x == 0) {
        float* o = psum + (b * NSUB + sub) * 4;
        o[0] = r[0][0] + r[0][1] + r[0][2] + r[0][3];
        o[1] = r[1][0] + r[1][1] + r[1][2] + r[1][3];
        o[2] = r[2][0] + r[2][1] + r[2][2] + r[2][3];
    }
}

// -------- precompute 2: per-(batch,sub) max squared radius + slot clear --------
__global__ __launch_bounds__(256) void max_kernel(const float* __restrict__ xyz,
                                                  const float* __restrict__ psum,
                                                  unsigned* __restrict__ pmax,
                                                  u64* __restrict__ slots) {
    if (blockIdx.x == 0) {                    // clear the 512 slot words (2 per thread)
        slots[threadIdx.x] = 0ull;
        slots[threadIdx.x + 256] = 0ull;
    }
    const int b   = blockIdx.x & 15;
    const int sub = blockIdx.x >> 4;
    const float* P = xyz + (size_t)b * NPTS * 3;
    float sx = 0.f, sy = 0.f, sz = 0.f;
    #pragma unroll
    for (int s = 0; s < NSUB; ++s) {          // fixed order: deterministic mean for all blocks
        sx += psum[(b * NSUB + s) * 4 + 0];
        sy += psum[(b * NSUB + s) * 4 + 1];
        sz += psum[(b * NSUB + s) * 4 + 2];
    }
    const float mx = sx / (float)NPTS, my = sy / (float)NPTS, mz = sz / (float)NPTS;
    float best = 0.f;
    for (int i = sub * 256 + threadIdx.x; i < NPTS; i += NSUB * 256) {
        float dx = P[i * 3 + 0] - mx;
        float dy = P[i * 3 + 1] - my;
        float dz = P[i * 3 + 2] - mz;
        best = fmaxf(best, dx * dx + dy * dy + dz * dz);
    }
    #pragma unroll
    for (int off = 32; off; off >>= 1) best = fmaxf(best, __shfl_xor(best, off));
    __shared__ float r[4];
    const int wave = threadIdx.x >> 6, lane = threadIdx.x & 63;
    if (lane == 0) r[wave] = best;
    __syncthreads();
    if (threadIdx.x == 0)
        pmax[b * NSUB + sub] = __float_as_uint(fmaxf(fmaxf(r[0], r[1]), fmaxf(r[2], r[3])));
}

// ---------------- main: FPS, 8 blocks/batch, block slots in one line ----------------
// Message word: [63:54] seq (=i+1), [53:22] float bits of max distance (>=0),
//               [21:0]  0x3FFFFF - idx (max-compare => smallest index on ties = np.argmax).
// Parity double-buffer, lag<=1: a seq i+3 store (same parity as i+1) requires its block
// to have finished the i+2 poll => all blocks stored i+2 => all finished the i+1 poll.
__global__ __launch_bounds__(512, 2) void fps_kernel(const float* __restrict__ xyz,
                                                     const float* __restrict__ cmap,
                                                     const int* __restrict__ init_far,
                                                     const unsigned* __restrict__ pmax,
                                                     u64* __restrict__ slots,
                                                     float* __restrict__ out) {
    const int b   = blockIdx.x & 15;   // batch (blocks {b, b+16, ...} -> XCD b%8)
    const int g   = blockIdx.x >> 4;   // block-in-batch 0..7
    const int tid = threadIdx.x;
    const int wave = tid >> 6, lane = tid & 63;
    const int tl  = g * TPB + tid;     // batch-local lane 0..4095
    const float* P = xyz + (size_t)b * NPTS * 3;

    // s_obj: deterministic reduce over the 16 partial maxes
    float m0 = 0.f;
    #pragma unroll
    for (int s = 0; s < NSUB; ++s) m0 = fmaxf(m0, __uint_as_float(pmax[b * NSUB + s]));
    const float sb = sqrtf(m0);

    // register-resident points (pairs, SLP-vectorizes to v_pk_* fp32) + running distances
    float pxx[NPAIR], pxy[NPAIR], pyx[NPAIR], pyy[NPAIR],
          pzx[NPAIR], pzy[NPAIR], pdx[NPAIR], pdy[NPAIR];
    #pragma unroll
    for (int j = 0; j < NPAIR; ++j) {
        const int p0 = tl + (2 * j) * STRIDE;
        const int p1 = tl + (2 * j + 1) * STRIDE;
        const bool v0 = p0 < NPTS, v1 = p1 < NPTS;
        pxx[j] = v0 ? P[p0 * 3 + 0] : 0.f;  pxy[j] = v1 ? P[p1 * 3 + 0] : 0.f;
        pyx[j] = v0 ? P[p0 * 3 + 1] : 0.f;  pyy[j] = v1 ? P[p1 * 3 + 1] : 0.f;
        pzx[j] = v0 ? P[p0 * 3 + 2] : 0.f;  pzy[j] = v1 ? P[p1 * 3 + 2] : 0.f;
        pdx[j] = v0 ? 1e10f : -1.0f;        pdy[j] = v1 ? 1e10f : -1.0f;
        // every lane owns >=24 valid points -> per-lane best always >= 0
    }

    __shared__ u64   lds_key[WPB];
    __shared__ int   lds_win;
    __shared__ float lds_x, lds_y, lds_z;
    __shared__ int   curhist[NPOINT];  // every block records the full selection history

    int cur = init_far[b];
    float cx = P[cur * 3 + 0], cy = P[cur * 3 + 1], cz = P[cur * 3 + 2];

    for (int i = 0; i < NPOINT; ++i) {
        if (tid == 448) curhist[i] = cur;          // wave 7, LDS only — off critical path
        if (i == NPOINT - 1) break;

        // ---- distance update + per-lane argmax (exact fp order match: no fma/contract) ----
        float best = -1.0f;
        int bidx = 0;
        {
            #pragma clang fp contract(off)
            #pragma unroll
            for (int j = 0; j < NPAIR; ++j) {
                float dx0 = pxx[j] - cx, dx1 = pxy[j] - cx;
                float dy0 = pyx[j] - cy, dy1 = pyy[j] - cy;
                float dz0 = pzx[j] - cz, dz1 = pzy[j] - cz;
                float s0 = dx0 * dx0 + dy0 * dy0;  float s1 = dx1 * dx1 + dy1 * dy1;
                s0 = s0 + dz0 * dz0;               s1 = s1 + dz1 * dz1;
                float n0 = fminf(pdx[j], s0);      float n1 = fminf(pdy[j], s1);
                pdx[j] = n0;                       pdy[j] = n1;
                if (n0 > best) { best = n0; bidx = tl + (2 * j) * STRIDE; }      // strict >
                if (n1 > best) { best = n1; bidx = tl + (2 * j + 1) * STRIDE; }  // => first max
            }
        }

        // ---- wave argmax (u64 butterfly; inverted idx -> smallest index on ties) ----
        const u64 want = (u64)(i + 1);
        u64 key = ((u64)__float_as_uint(best) << 22) | (u64)(0x3FFFFFu - (unsigned)bidx);
        #pragma unroll
        for (int off = 32; off; off >>= 1) {
            u64 o2 = __shfl_xor(key, off);
            key = o2 > key ? o2 : key;
        }
        if (lane == 0) lds_key[wave] = key;
        __syncthreads();   // syncA

        u64* const bs = slots + ((size_t)(i & 1) * NBATCH + b) * SLOTPAD;

        if (wave == 0) {
            // block reduce (lanes 0..7, 3-hop), lane 0 publishes the slot
            u64 bk = (lane < WPB) ? lds_key[lane] : 0;
            #pragma unroll
            for (int off = 1; off < WPB; off <<= 1) {
                u64 o2 = __shfl_xor(bk, off);
                bk = o2 > bk ? o2 : bk;
            }
            if (lane == 0)
                __hip_atomic_store(&bs[g], bk | (want << 54),
                                   __ATOMIC_RELAXED, __HIP_MEMORY_SCOPE_AGENT);

            // poll the 8 slots (one half-line): one atomic load + one waitcnt per round
            u64 v = 0;
            if (lane < GPB) {
                u64* sp = &bs[lane];
                int tries = 0;
                for (;;) {
                    v = __hip_atomic_load(sp, __ATOMIC_RELAXED, __HIP_MEMORY_SCOPE_AGENT);
                    if ((v >> 54) >= want) break;
                    if (++tries > 16) __builtin_amdgcn_s_sleep(1);
                }
            }
            // prefetch candidate coords (L2-hot) BEFORE the reduce — hides the tail gather
            const int ci = (int)(0x3FFFFFu - (unsigned)(v & 0x3FFFFFu));
            float gx = 0.f, gy = 0.f, gz = 0.f;
            if (lane < GPB) {
                gx = P[ci * 3 + 0];
                gy = P[ci * 3 + 1];
                gz = P[ci * 3 + 2];
            }
            // 3-hop argmax over the 8 gate words (groups of 8; group 0 holds the answer)
            u64 kk = v;
            #pragma unroll
            for (int off = 1; off < GPB; off <<= 1) {
                u64 o2 = __shfl_xor(kk, off);
                kk = o2 > kk ? o2 : kk;
            }
            // winner slot's poller lane holds everything -> writes LDS directly
            if (lane < GPB && v == kk) {   // idx unique across blocks -> exactly one lane
                lds_win = ci;
                lds_x = gx; lds_y = gy; lds_z = gz;
            }
        }
        __syncthreads();   // syncB
        cur = lds_win;
        cx = lds_x; cy = lds_y; cz = lds_z;   // coords from the poller's prefetch — no gather
    }

    // ---------------- deferred output pass: 128 rows per block ----------------
    __syncthreads();                   // curhist fully written
    if (tid < 128) {
        const int row = g * 128 + tid; // 8 blocks x 128 rows = 1024
        const int c   = curhist[row];
        const float cm = cmap[(size_t)b * NPTS + c];
        const float x = P[c * 3 + 0], y = P[c * 3 + 1], z = P[c * 3 + 2];
        float* o = out + ((size_t)b * NPOINT + row) * 4;
        o[0] = cm;
        o[1] = x / sb;
        o[2] = y / sb;
        o[3] = z / sb;
    }
}

extern "C" void kernel_launch(void* const* d_in, const int* in_sizes, int n_in,
                              void* d_out, int out_size, void* d_ws, size_t ws_size,
                              hipStream_t stream) {
    const float* mesh = (const float*)d_in[0];
    const float* cmap = (const float*)d_in[1];
    const int* init   = (const int*)d_in[2];
    float* out = (float*)d_out;

    char* ws      = (char*)d_ws;
    float* psum   = (float*)ws;
    unsigned* pmx = (unsigned*)(ws + 4096);
    u64* slots    = (u64*)(ws + 8192);

    sum_kernel<<<dim3(256), dim3(256), 0, stream>>>(mesh, psum);
    max_kernel<<<dim3(256), dim3(256), 0, stream>>>(mesh, psum, pmx, slots);
    fps_kernel<<<dim3(NBATCH * GPB), dim3(TPB), 0, stream>>>(mesh, cmap, init, pmx, slots, out);
}

// Round 10
// 2012.195 us; speedup vs baseline: 2.1099x; 1.2203x over previous
//
#include <hip/hip_runtime.h>
#include <cstdint>

#define NBATCH 16
#define NPOINT 1024
#define NPTS   100000
#define GPB    16            // blocks per batch
#define TPB    256           // threads per block (4 waves)
#define WPB    4
#define NSUB   16            // sub-blocks per batch in precompute kernels
#define STRIDE (GPB * TPB)   // 4096 threads per batch
#define KPT    25            // points per thread
#define NPAIR  13            // KPT as float pairs (last half-padded)

typedef unsigned long long u64;

// d_ws layout (no host memset needed):
//   @0    : float psum[16][16][4]  (4 KB) — per-(batch,sub) partial coord sums (plain stores)
//   @4096 : uint  pmax[16][16]     (1 KB) — per-(batch,sub) partial max sq-radius (plain stores)
//   @8192 : u64   slots[2][16][16] (4 KB) — per-(parity,batch,block) argmax msg;
//                                           zeroed by max_kernel block 0 (poisoned seq would
//                                           false-accept, so this clear is mandatory)

// ---------------- precompute 1: per-(batch,sub) coordinate sums ----------------
__global__ __launch_bounds__(256) void sum_kernel(const float* __restrict__ xyz,
                                                  float* __restrict__ psum) {
    const int b   = blockIdx.x & 15;
    const int sub = blockIdx.x >> 4;          // 0..15
    const float* P = xyz + (size_t)b * NPTS * 3;
    float sx = 0.f, sy = 0.f, sz = 0.f;
    for (int i = sub * TPB + threadIdx.x; i < NPTS; i += NSUB * TPB) {
        sx += P[i * 3 + 0];
        sy += P[i * 3 + 1];
        sz += P[i * 3 + 2];
    }
    #pragma unroll
    for (int off = 32; off; off >>= 1) {
        sx += __shfl_xor(sx, off);
        sy += __shfl_xor(sy, off);
        sz += __shfl_xor(sz, off);
    }
    __shared__ float r[3][4];
    const int wave = threadIdx.x >> 6, lane = threadIdx.x & 63;
    if (lane == 0) { r[0][wave] = sx; r[1][wave] = sy; r[2][wave] = sz; }
    __syncthreads();
    if (threadIdx.x == 0) {
        float* o = psum + (b * NSUB + sub) * 4;
        o[0] = r[0][0] + r[0][1] + r[0][2] + r[0][3];
        o[1] = r[1][0] + r[1][1] + r[1][2] + r[1][3];
        o[2] = r[2][0] + r[2][1] + r[2][2] + r[2][3];
    }
}

// -------- precompute 2: per-(batch,sub) max squared radius + slot clear --------
__global__ __launch_bounds__(256) void max_kernel(const float* __restrict__ xyz,
                                                  const float* __restrict__ psum,
                                                  unsigned* __restrict__ pmax,
                                                  u64* __restrict__ slots) {
    if (blockIdx.x == 0) {                    // clear the 512 message slots (2 per thread)
        slots[threadIdx.x] = 0ull;
        slots[threadIdx.x + 256] = 0ull;
    }
    const int b   = blockIdx.x & 15;
    const int sub = blockIdx.x >> 4;
    const float* P = xyz + (size_t)b * NPTS * 3;
    float sx = 0.f, sy = 0.f, sz = 0.f;
    #pragma unroll
    for (int s = 0; s < NSUB; ++s) {          // fixed order: deterministic mean for all blocks
        sx += psum[(b * NSUB + s) * 4 + 0];
        sy += psum[(b * NSUB + s) * 4 + 1];
        sz += psum[(b * NSUB + s) * 4 + 2];
    }
    const float mx = sx / (float)NPTS, my = sy / (float)NPTS, mz = sz / (float)NPTS;
    float best = 0.f;
    for (int i = sub * TPB + threadIdx.x; i < NPTS; i += NSUB * TPB) {
        float dx = P[i * 3 + 0] - mx;
        float dy = P[i * 3 + 1] - my;
        float dz = P[i * 3 + 2] - mz;
        best = fmaxf(best, dx * dx + dy * dy + dz * dz);
    }
    #pragma unroll
    for (int off = 32; off; off >>= 1) best = fmaxf(best, __shfl_xor(best, off));
    __shared__ float r[4];
    const int wave = threadIdx.x >> 6, lane = threadIdx.x & 63;
    if (lane == 0) r[wave] = best;
    __syncthreads();
    if (threadIdx.x == 0)
        pmax[b * NSUB + sub] = __float_as_uint(fmaxf(fmaxf(r[0], r[1]), fmaxf(r[2], r[3])));
}

// ---------------- main: FPS, 4 phase-offset poller waves per block ----------------
// Message word: [63:54] seq (=i+1), [53:22] float bits of max distance (>=0),
//               [21:0]  0x3FFFFF - idx (max-compare => smallest index on ties = np.argmax).
// Parity double-buffer, lag<=1: a seq i+3 store (same parity as i+1) requires its block
// to have finished the i+2 poll => all blocks stored i+2 => all finished the i+1 poll.
// LDS result (lds_win/x/y/z) race-freedom: writes for iter i+1 happen after syncA(i+1),
// which every wave reaches only after reading the iter-i result (read is before compute);
// reads for iter i happen after syncB(i), after every wave's iter-i write.
__global__ __launch_bounds__(256, 1) void fps_kernel(const float* __restrict__ xyz,
                                                     const float* __restrict__ cmap,
                                                     const int* __restrict__ init_far,
                                                     const unsigned* __restrict__ pmax,
                                                     u64* __restrict__ slots,
                                                     float* __restrict__ out) {
    const int b   = blockIdx.x & 15;   // batch
    const int g   = blockIdx.x >> 4;   // block-in-batch 0..15
    const int tid = threadIdx.x;
    const int wave = tid >> 6, lane = tid & 63;
    const int tl  = g * TPB + tid;     // batch-local lane 0..4095
    const float* P = xyz + (size_t)b * NPTS * 3;

    // s_obj: deterministic reduce over the 16 partial maxes
    float m0 = 0.f;
    #pragma unroll
    for (int s = 0; s < NSUB; ++s) m0 = fmaxf(m0, __uint_as_float(pmax[b * NSUB + s]));
    const float sb = sqrtf(m0);

    // register-resident points (pairs, SLP-vectorizes to v_pk_* fp32) + running distances
    float pxx[NPAIR], pxy[NPAIR], pyx[NPAIR], pyy[NPAIR],
          pzx[NPAIR], pzy[NPAIR], pdx[NPAIR], pdy[NPAIR];
    #pragma unroll
    for (int j = 0; j < NPAIR; ++j) {
        const int p0 = tl + (2 * j) * STRIDE;
        const int p1 = tl + (2 * j + 1) * STRIDE;
        const bool v0 = p0 < NPTS, v1 = p1 < NPTS;
        pxx[j] = v0 ? P[p0 * 3 + 0] : 0.f;  pxy[j] = v1 ? P[p1 * 3 + 0] : 0.f;
        pyx[j] = v0 ? P[p0 * 3 + 1] : 0.f;  pyy[j] = v1 ? P[p1 * 3 + 1] : 0.f;
        pzx[j] = v0 ? P[p0 * 3 + 2] : 0.f;  pzy[j] = v1 ? P[p1 * 3 + 2] : 0.f;
        pdx[j] = v0 ? 1e10f : -1.0f;        pdy[j] = v1 ? 1e10f : -1.0f;
        // every lane owns >=24 valid points -> per-lane best always >= 0
    }

    __shared__ u64   lds_key[WPB];
    __shared__ int   lds_win;
    __shared__ float lds_x, lds_y, lds_z;
    __shared__ int   curhist[NPOINT];  // every block records the full selection history

    int cur = init_far[b];
    float cx = P[cur * 3 + 0], cy = P[cur * 3 + 1], cz = P[cur * 3 + 2];

    for (int i = 0; i < NPOINT; ++i) {
        if (tid == 192) curhist[i] = cur;          // wave 3, LDS only — off critical path
        if (i == NPOINT - 1) break;

        // ---- distance update + per-lane argmax (exact fp order match: no fma/contract) ----
        float best = -1.0f;
        int bidx = 0;
        {
            #pragma clang fp contract(off)
            #pragma unroll
            for (int j = 0; j < NPAIR; ++j) {
                float dx0 = pxx[j] - cx, dx1 = pxy[j] - cx;
                float dy0 = pyx[j] - cy, dy1 = pyy[j] - cy;
                float dz0 = pzx[j] - cz, dz1 = pzy[j] - cz;
                float s0 = dx0 * dx0 + dy0 * dy0;  float s1 = dx1 * dx1 + dy1 * dy1;
                s0 = s0 + dz0 * dz0;               s1 = s1 + dz1 * dz1;
                float n0 = fminf(pdx[j], s0);      float n1 = fminf(pdy[j], s1);
                pdx[j] = n0;                       pdy[j] = n1;
                if (n0 > best) { best = n0; bidx = tl + (2 * j) * STRIDE; }      // strict >
                if (n1 > best) { best = n1; bidx = tl + (2 * j + 1) * STRIDE; }  // => first max
            }
        }

        // ---- wave argmax (u64 butterfly; inverted idx -> smallest index on ties) ----
        const u64 want = (u64)(i + 1);
        u64 key = ((u64)__float_as_uint(best) << 22) | (u64)(0x3FFFFFu - (unsigned)bidx);
        #pragma unroll
        for (int off = 32; off; off >>= 1) {
            u64 o2 = __shfl_xor(key, off);
            key = o2 > key ? o2 : key;
        }
        if (lane == 0) lds_key[wave] = key;
        __syncthreads();   // syncA

        u64* const bs = slots + ((size_t)(i & 1) * NBATCH + b) * GPB;

        if (wave == 0) {
            // block reduce (lanes 0..3, 2-hop), lane 0 publishes the slot
            u64 bk = (lane < WPB) ? lds_key[lane] : 0;
            #pragma unroll
            for (int off = 1; off < WPB; off <<= 1) {
                u64 o2 = __shfl_xor(bk, off);
                bk = o2 > bk ? o2 : bk;
            }
            if (lane == 0)
                __hip_atomic_store(&bs[g], bk | (want << 54),
                                   __ATOMIC_RELAXED, __HIP_MEMORY_SCOPE_AGENT);
        }

        // ---- ALL FOUR WAVES poll (phase-offset samplers of the same 128-B line) ----
        u64 v = 0;
        int ci = 0;
        float gx = 0.f, gy = 0.f, gz = 0.f;
        if (lane < GPB) {
            u64* sp = &bs[lane];
            int tries = 0;
            for (;;) {
                v = __hip_atomic_load(sp, __ATOMIC_RELAXED, __HIP_MEMORY_SCOPE_AGENT);
                if ((v >> 54) >= want) break;
                if (++tries > 64) __builtin_amdgcn_s_sleep(1);
            }
            // prefetch candidate coords (L2-hot) BEFORE the reduce — hides the tail gather
            ci = (int)(0x3FFFFFu - (unsigned)(v & 0x3FFFFFu));
            gx = P[ci * 3 + 0];
            gy = P[ci * 3 + 1];
            gz = P[ci * 3 + 2];
        }
        // 4-hop argmax over the 16 gate words (within 16-lane groups; group 0 has the data)
        u64 kk = v;
        #pragma unroll
        for (int off = 8; off; off >>= 1) {
            u64 o2 = __shfl_xor(kk, off);
            kk = o2 > kk ? o2 : kk;
        }
        // winner slot's poller lane holds everything -> writes LDS directly.
        // All 4 waves write the same values at different times (benign duplication).
        if (lane < GPB && v == kk) {   // idx unique across blocks -> one lane per wave
            lds_win = ci;
            lds_x = gx; lds_y = gy; lds_z = gz;
        }
        __syncthreads();   // syncB
        cur = lds_win;
        cx = lds_x; cy = lds_y; cz = lds_z;   // coords from the pollers' prefetch — no gather
    }

    // ---------------- deferred output pass: 64 rows per block ----------------
    __syncthreads();                   // curhist fully written
    if (tid < 64) {
        const int row = g * 64 + tid;  // 16 blocks x 64 rows = 1024
        const int c   = curhist[row];
        const float cm = cmap[(size_t)b * NPTS + c];
        const float x = P[c * 3 + 0], y = P[c * 3 + 1], z = P[c * 3 + 2];
        float* o = out + ((size_t)b * NPOINT + row) * 4;
        o[0] = cm;
        o[1] = x / sb;
        o[2] = y / sb;
        o[3] = z / sb;
    }
}

extern "C" void kernel_launch(void* const* d_in, const int* in_sizes, int n_in,
                              void* d_out, int out_size, void* d_ws, size_t ws_size,
                              hipStream_t stream) {
    const float* mesh = (const float*)d_in[0];
    const float* cmap = (const float*)d_in[1];
    const int* init   = (const int*)d_in[2];
    float* out = (float*)d_out;

    char* ws      = (char*)d_ws;
    float* psum   = (float*)ws;
    unsigned* pmx = (unsigned*)(ws + 4096);
    u64* slots    = (u64*)(ws + 8192);

    sum_kernel<<<dim3(256), dim3(TPB), 0, stream>>>(mesh, psum);
    max_kernel<<<dim3(256), dim3(TPB), 0, stream>>>(mesh, psum, pmx, slots);
    fps_kernel<<<dim3(256), dim3(TPB), 0, stream>>>(mesh, cmap, init, pmx, slots, out);
}

// Round 11
// 1995.367 us; speedup vs baseline: 2.1277x; 1.0084x over previous
//
#include <hip/hip_runtime.h>
#include <cstdint>

#define NBATCH 16
#define NPOINT 1024
#define NPTS   100000
#define GPB    16            // blocks per batch
#define TPB    256           // threads per block (4 waves)
#define WPB    4
#define NSUB   16            // sub-blocks per batch in precompute kernels
#define STRIDE (GPB * TPB)   // 4096 threads per batch
#define KPT    25            // points per thread
#define NPAIR  13            // KPT as float pairs (last half-padded)
#define LPAD   16            // u64s per slot -> each block slot owns a full 128-B line

typedef unsigned long long u64;

// d_ws layout (no host memset needed):
//   @0    : float psum[16][16][4]        (4 KB)  — per-(batch,sub) partial coord sums
//   @4096 : uint  pmax[16][16]           (1 KB)  — per-(batch,sub) partial max sq-radius
//   @8192 : u64   slots[2][16][16][LPAD] (64 KB) — per-(parity,batch,block) argmax msg,
//                 ONE 128-B LINE PER SLOT (no line shared by two writers / two batches);
//                 zeroed by max_kernel block 0 (poisoned seq would false-accept).

// ---------------- precompute 1: per-(batch,sub) coordinate sums ----------------
__global__ __launch_bounds__(256) void sum_kernel(const float* __restrict__ xyz,
                                                  float* __restrict__ psum) {
    const int b   = blockIdx.x & 15;
    const int sub = blockIdx.x >> 4;          // 0..15
    const float* P = xyz + (size_t)b * NPTS * 3;
    float sx = 0.f, sy = 0.f, sz = 0.f;
    for (int i = sub * TPB + threadIdx.x; i < NPTS; i += NSUB * TPB) {
        sx += P[i * 3 + 0];
        sy += P[i * 3 + 1];
        sz += P[i * 3 + 2];
    }
    #pragma unroll
    for (int off = 32; off; off >>= 1) {
        sx += __shfl_xor(sx, off);
        sy += __shfl_xor(sy, off);
        sz += __shfl_xor(sz, off);
    }
    __shared__ float r[3][4];
    const int wave = threadIdx.x >> 6, lane = threadIdx.x & 63;
    if (lane == 0) { r[0][wave] = sx; r[1][wave] = sy; r[2][wave] = sz; }
    __syncthreads();
    if (threadIdx.x == 0) {
        float* o = psum + (b * NSUB + sub) * 4;
        o[0] = r[0][0] + r[0][1] + r[0][2] + r[0][3];
        o[1] = r[1][0] + r[1][1] + r[1][2] + r[1][3];
        o[2] = r[2][0] + r[2][1] + r[2][2] + r[2][3];
    }
}

// -------- precompute 2: per-(batch,sub) max squared radius + slot clear --------
__global__ __launch_bounds__(256) void max_kernel(const float* __restrict__ xyz,
                                                  const float* __restrict__ psum,
                                                  unsigned* __restrict__ pmax,
                                                  u64* __restrict__ slots) {
    if (blockIdx.x == 0) {                    // clear 8192 slot words (32 per thread)
        #pragma unroll
        for (int q = 0; q < 32; ++q) slots[threadIdx.x + q * 256] = 0ull;
    }
    const int b   = blockIdx.x & 15;
    const int sub = blockIdx.x >> 4;
    const float* P = xyz + (size_t)b * NPTS * 3;
    float sx = 0.f, sy = 0.f, sz = 0.f;
    #pragma unroll
    for (int s = 0; s < NSUB; ++s) {          // fixed order: deterministic mean for all blocks
        sx += psum[(b * NSUB + s) * 4 + 0];
        sy += psum[(b * NSUB + s) * 4 + 1];
        sz += psum[(b * NSUB + s) * 4 + 2];
    }
    const float mx = sx / (float)NPTS, my = sy / (float)NPTS, mz = sz / (float)NPTS;
    float best = 0.f;
    for (int i = sub * TPB + threadIdx.x; i < NPTS; i += NSUB * TPB) {
        float dx = P[i * 3 + 0] - mx;
        float dy = P[i * 3 + 1] - my;
        float dz = P[i * 3 + 2] - mz;
        best = fmaxf(best, dx * dx + dy * dy + dz * dz);
    }
    #pragma unroll
    for (int off = 32; off; off >>= 1) best = fmaxf(best, __shfl_xor(best, off));
    __shared__ float r[4];
    const int wave = threadIdx.x >> 6, lane = threadIdx.x & 63;
    if (lane == 0) r[wave] = best;
    __syncthreads();
    if (threadIdx.x == 0)
        pmax[b * NSUB + sub] = __float_as_uint(fmaxf(fmaxf(r[0], r[1]), fmaxf(r[2], r[3])));
}

// ---------------- main: FPS, one 128-B line per block slot ----------------
// Message word: [63:54] seq (=i+1), [53:22] float bits of max distance (>=0),
//               [21:0]  0x3FFFFF - idx (max-compare => smallest index on ties = np.argmax).
// Parity double-buffer, lag<=1: a seq i+3 store (same parity as i+1) requires its block
// to have finished the i+2 poll => all blocks stored i+2 => all finished the i+1 poll.
__global__ __launch_bounds__(256, 1) void fps_kernel(const float* __restrict__ xyz,
                                                     const float* __restrict__ cmap,
                                                     const int* __restrict__ init_far,
                                                     const unsigned* __restrict__ pmax,
                                                     u64* __restrict__ slots,
                                                     float* __restrict__ out) {
    const int b   = blockIdx.x & 15;   // batch (all 16 blocks of a batch on XCD b%8)
    const int g   = blockIdx.x >> 4;   // block-in-batch 0..15
    const int tid = threadIdx.x;
    const int wave = tid >> 6, lane = tid & 63;
    const int tl  = g * TPB + tid;     // batch-local lane 0..4095
    const float* P = xyz + (size_t)b * NPTS * 3;

    // s_obj: deterministic reduce over the 16 partial maxes
    float m0 = 0.f;
    #pragma unroll
    for (int s = 0; s < NSUB; ++s) m0 = fmaxf(m0, __uint_as_float(pmax[b * NSUB + s]));
    const float sb = sqrtf(m0);

    // register-resident points (pairs, SLP-vectorizes to v_pk_* fp32) + running distances
    float pxx[NPAIR], pxy[NPAIR], pyx[NPAIR], pyy[NPAIR],
          pzx[NPAIR], pzy[NPAIR], pdx[NPAIR], pdy[NPAIR];
    #pragma unroll
    for (int j = 0; j < NPAIR; ++j) {
        const int p0 = tl + (2 * j) * STRIDE;
        const int p1 = tl + (2 * j + 1) * STRIDE;
        const bool v0 = p0 < NPTS, v1 = p1 < NPTS;
        pxx[j] = v0 ? P[p0 * 3 + 0] : 0.f;  pxy[j] = v1 ? P[p1 * 3 + 0] : 0.f;
        pyx[j] = v0 ? P[p0 * 3 + 1] : 0.f;  pyy[j] = v1 ? P[p1 * 3 + 1] : 0.f;
        pzx[j] = v0 ? P[p0 * 3 + 2] : 0.f;  pzy[j] = v1 ? P[p1 * 3 + 2] : 0.f;
        pdx[j] = v0 ? 1e10f : -1.0f;        pdy[j] = v1 ? 1e10f : -1.0f;
        // every lane owns >=24 valid points -> per-lane best always >= 0
    }

    __shared__ u64   lds_key[WPB];
    __shared__ int   lds_win;
    __shared__ float lds_x, lds_y, lds_z;
    __shared__ int   curhist[NPOINT];  // every block records the full selection history

    int cur = init_far[b];
    float cx = P[cur * 3 + 0], cy = P[cur * 3 + 1], cz = P[cur * 3 + 2];

    for (int i = 0; i < NPOINT; ++i) {
        if (tid == 192) curhist[i] = cur;          // wave 3, LDS only — off critical path
        if (i == NPOINT - 1) break;

        // ---- distance update + per-lane argmax (exact fp order match: no fma/contract) ----
        float best = -1.0f;
        int bidx = 0;
        {
            #pragma clang fp contract(off)
            #pragma unroll
            for (int j = 0; j < NPAIR; ++j) {
                float dx0 = pxx[j] - cx, dx1 = pxy[j] - cx;
                float dy0 = pyx[j] - cy, dy1 = pyy[j] - cy;
                float dz0 = pzx[j] - cz, dz1 = pzy[j] - cz;
                float s0 = dx0 * dx0 + dy0 * dy0;  float s1 = dx1 * dx1 + dy1 * dy1;
                s0 = s0 + dz0 * dz0;               s1 = s1 + dz1 * dz1;
                float n0 = fminf(pdx[j], s0);      float n1 = fminf(pdy[j], s1);
                pdx[j] = n0;                       pdy[j] = n1;
                if (n0 > best) { best = n0; bidx = tl + (2 * j) * STRIDE; }      // strict >
                if (n1 > best) { best = n1; bidx = tl + (2 * j + 1) * STRIDE; }  // => first max
            }
        }

        // ---- wave argmax (u64 butterfly; inverted idx -> smallest index on ties) ----
        const u64 want = (u64)(i + 1);
        u64 key = ((u64)__float_as_uint(best) << 22) | (u64)(0x3FFFFFu - (unsigned)bidx);
        #pragma unroll
        for (int off = 32; off; off >>= 1) {
            u64 o2 = __shfl_xor(key, off);
            key = o2 > key ? o2 : key;
        }
        if (lane == 0) lds_key[wave] = key;
        __syncthreads();   // syncA

        u64* const bs = slots + ((size_t)(i & 1) * NBATCH + b) * (GPB * LPAD);

        if (wave == 0) {
            // block reduce (lanes 0..3, 2-hop), lane 0 publishes this block's private line
            u64 bk = (lane < WPB) ? lds_key[lane] : 0;
            #pragma unroll
            for (int off = 1; off < WPB; off <<= 1) {
                u64 o2 = __shfl_xor(bk, off);
                bk = o2 > bk ? o2 : bk;
            }
            if (lane == 0)
                __hip_atomic_store(&bs[g * LPAD], bk | (want << 54),
                                   __ATOMIC_RELAXED, __HIP_MEMORY_SCOPE_AGENT);

            // poll: lane l watches line l — 16 independent line fetches, one waitcnt/round
            u64 v = 0;
            if (lane < GPB) {
                u64* sp = &bs[lane * LPAD];
                int tries = 0;
                for (;;) {
                    v = __hip_atomic_load(sp, __ATOMIC_RELAXED, __HIP_MEMORY_SCOPE_AGENT);
                    if ((v >> 54) >= want) break;
                    if (++tries > 16) __builtin_amdgcn_s_sleep(1);
                }
            }
            // prefetch candidate coords (L2-hot) BEFORE the reduce — hides the tail gather
            const int ci = (int)(0x3FFFFFu - (unsigned)(v & 0x3FFFFFu));
            float gx = 0.f, gy = 0.f, gz = 0.f;
            if (lane < GPB) {
                gx = P[ci * 3 + 0];
                gy = P[ci * 3 + 1];
                gz = P[ci * 3 + 2];
            }
            // 4-hop argmax over the 16 gate words (within 16-lane group)
            u64 kk = v;
            #pragma unroll
            for (int off = 8; off; off >>= 1) {
                u64 o2 = __shfl_xor(kk, off);
                kk = o2 > kk ? o2 : kk;
            }
            // winner slot's poller lane holds everything -> writes LDS directly
            if (lane < GPB && v == kk) {   // idx unique across blocks -> exactly one lane
                lds_win = ci;
                lds_x = gx; lds_y = gy; lds_z = gz;
            }
        }
        __syncthreads();   // syncB
        cur = lds_win;
        cx = lds_x; cy = lds_y; cz = lds_z;   // coords from the poller's prefetch — no gather
    }

    // ---------------- deferred output pass: 64 rows per block ----------------
    __syncthreads();                   // curhist fully written
    if (tid < 64) {
        const int row = g * 64 + tid;  // 16 blocks x 64 rows = 1024
        const int c   = curhist[row];
        const float cm = cmap[(size_t)b * NPTS + c];
        const float x = P[c * 3 + 0], y = P[c * 3 + 1], z = P[c * 3 + 2];
        float* o = out + ((size_t)b * NPOINT + row) * 4;
        o[0] = cm;
        o[1] = x / sb;
        o[2] = y / sb;
        o[3] = z / sb;
    }
}

extern "C" void kernel_launch(void* const* d_in, const int* in_sizes, int n_in,
                              void* d_out, int out_size, void* d_ws, size_t ws_size,
                              hipStream_t stream) {
    const float* mesh = (const float*)d_in[0];
    const float* cmap = (const float*)d_in[1];
    const int* init   = (const int*)d_in[2];
    float* out = (float*)d_out;

    char* ws      = (char*)d_ws;
    float* psum   = (float*)ws;
    unsigned* pmx = (unsigned*)(ws + 4096);
    u64* slots    = (u64*)(ws + 8192);    // 64 KB: one 128-B line per (parity,batch,block)

    sum_kernel<<<dim3(256), dim3(TPB), 0, stream>>>(mesh, psum);
    max_kernel<<<dim3(256), dim3(TPB), 0, stream>>>(mesh, psum, pmx, slots);
    fps_kernel<<<dim3(256), dim3(TPB), 0, stream>>>(mesh, cmap, init, pmx, slots, out);
}